// Round 12
// baseline (530.570 us; speedup 1.0000x reference)
//
#include <hip/hip_runtime.h>
#include <hip/hip_cooperative_groups.h>

namespace cg = cooperative_groups;

#define Bdim 32
#define Tdim 256
#define Cdim 1024

typedef unsigned short u16;
typedef unsigned int u32;
typedef __bf16 bf16x8 __attribute__((ext_vector_type(8)));
typedef float f32x4 __attribute__((ext_vector_type(4)));

__device__ __forceinline__ float bf2f(u32 u) {
    union { u32 i; float f; } v; v.i = u << 16; return v.f;
}
__device__ __forceinline__ u16 f2bf(float f) {
    union { float f; u32 i; } v; v.f = f;
    u32 u = v.i;
    return (u16)((u + 0x7fffu + ((u >> 16) & 1u)) >> 16);  // RNE
}

__device__ __forceinline__ void gload16(const u16* g, u16* l) {
    __builtin_amdgcn_global_load_lds(
        (__attribute__((address_space(1))) const void*)g,
        (__attribute__((address_space(3))) void*)l, 16, 0, 0);
}

// ---- prep body (x mixing -> bf16, weight convert), virtual-block -------------
__device__ __forceinline__ void prep_body(
    int bid, int tx,
    const float* x, const float* tmk, const float* tmv, const float* tmr,
    u16* xk, u16* xv, u16* xr,
    const float* w0, const float* w1, const float* w2, const float* w3,
    u16* o0, u16* o1, u16* o2, u16* o3)
{
    if (bid < 4096) {
        int tid = bid * 256 + tx;
        int e = tid << 3;
        int c = e & (Cdim - 1);
        int t = (e >> 10) & (Tdim - 1);
        float xf[8], xxf[8], mk[8], mv[8], mr[8];
        *(float4*)(xf)     = *(const float4*)(x + e);
        *(float4*)(xf + 4) = *(const float4*)(x + e + 4);
        if (t != 0) {
            *(float4*)(xxf)     = *(const float4*)(x + e - Cdim);
            *(float4*)(xxf + 4) = *(const float4*)(x + e - Cdim + 4);
        } else {
#pragma unroll
            for (int j = 0; j < 8; j++) xxf[j] = 0.f;
        }
        *(float4*)(mk)     = *(const float4*)(tmk + c);
        *(float4*)(mk + 4) = *(const float4*)(tmk + c + 4);
        *(float4*)(mv)     = *(const float4*)(tmv + c);
        *(float4*)(mv + 4) = *(const float4*)(tmv + c + 4);
        *(float4*)(mr)     = *(const float4*)(tmr + c);
        *(float4*)(mr + 4) = *(const float4*)(tmr + c + 4);
        u16 ok[8], ov[8], orr[8];
#pragma unroll
        for (int j = 0; j < 8; j++) {
            float d = xf[j] - xxf[j];
            ok[j]  = f2bf(xxf[j] + d * mk[j]);
            ov[j]  = f2bf(xxf[j] + d * mv[j]);
            orr[j] = f2bf(xxf[j] + d * mr[j]);
        }
        *(uint4*)(xk + e) = *(const uint4*)ok;
        *(uint4*)(xv + e) = *(const uint4*)ov;
        *(uint4*)(xr + e) = *(const uint4*)orr;
    } else {
        int wb = bid - 4096;                 // 0..2047
        int m = wb >> 9;                     // matrix 0..3
        const float* src; u16* dst;
        switch (m) {
            case 0: src = w0; dst = o0; break;
            case 1: src = w1; dst = o1; break;
            case 2: src = w2; dst = o2; break;
            default: src = w3; dst = o3; break;
        }
        int i = (((wb & 511) << 8) + tx) << 3;
        float a[8];
        *(float4*)(a)     = *(const float4*)(src + i);
        *(float4*)(a + 4) = *(const float4*)(src + i + 4);
        u16 o[8];
#pragma unroll
        for (int j = 0; j < 8; j++) o[j] = f2bf(a[j]);
        *(uint4*)(dst + i) = *(const uint4*)o;
    }
}

// ---- GEMM body: r4/r8 verified (61.9 us, MfmaUtil 34, 0 bank conflicts) ------
// 128x128 tile, BK=64, 4 waves (2Mx2N), dbuf LDS 2x32KiB, one-tile-ahead
// prefetch, __syncthreads tile boundaries (fence-safe; r5 race lesson).
// ROTATION SWIZZLE (r0-verified): slot (row,pos) holds k-chunk
// (pos+((row>>1)&3))&3; writer thread t fetches chunk ((t&3)+((t>>3)&3))&3;
// reader lane (fr,quad) reads pos=(quad-((fr>>1)&3))&3.
template <int BF16OUT>
__device__ __forceinline__ void gemm_body(
    const u16* A, const u16* Bw, void* Cout, u16* Ls, int bm, int bn)
{
    const int K = Cdim, N = Cdim;
    const int NT = K / 64;                   // 16 K-tiles
    const int tid = threadIdx.x;
    const int lane = tid & 63, wave = tid >> 6;
    const int wm = (wave & 1) << 6, wn = (wave >> 1) << 6;
    const int fr = lane & 15, quad = lane >> 4;

    const int srow = tid >> 2;
    const int skc = ((((tid & 3) + ((tid >> 3) & 3)) & 3) << 3);  // rotated chunk
    const u16* ga = A + (size_t)(bm * 128 + srow) * K + skc;
    const u16* gb = Bw + (size_t)(bn * 128 + srow) * K + skc;
    const size_t gstep = (size_t)64 * K;
    const int lw = wave << 9;                // wave-uniform LDS base (u16)

    auto stage = [&](int t, int buf) {
        const u16* gat = ga + t * 64;
        const u16* gbt = gb + t * 64;
        u16* base = Ls + buf * 16384 + lw;
        gload16(gat,              base);
        gload16(gat + gstep,      base + 2048);
        gload16(gbt,              base + 4096);
        gload16(gbt + gstep,      base + 4096 + 2048);
        gload16(gat + 32,         base + 8192);
        gload16(gat + 32 + gstep, base + 8192 + 2048);
        gload16(gbt + 32,         base + 12288);
        gload16(gbt + 32 + gstep, base + 12288 + 2048);
    };

    f32x4 acc[4][4];
#pragma unroll
    for (int i = 0; i < 4; i++)
#pragma unroll
        for (int j = 0; j < 4; j++)
            acc[i][j] = (f32x4){0.f, 0.f, 0.f, 0.f};

    const int rq = (((quad - ((fr >> 1) & 3)) & 3) << 3);  // reader pos (u16)

    stage(0, 0);
    __syncthreads();
    __builtin_amdgcn_sched_barrier(0);

#pragma unroll 1
    for (int t = 0; t < NT; ++t) {
        const int buf = t & 1;
        if (t + 1 < NT) stage(t + 1, buf ^ 1);   // prefetch next tile
        const u16* Tb = Ls + buf * 16384;
#pragma unroll
        for (int h = 0; h < 2; h++) {
            const u16* Ah = Tb + h * 8192;
            const u16* Bh = Tb + 4096 + h * 8192;
            bf16x8 af[4], bfr[4];
#pragma unroll
            for (int i = 0; i < 4; i++) {
                af[i]  = *(const bf16x8*)(Ah + (wm + i * 16 + fr) * 32 + rq);
                bfr[i] = *(const bf16x8*)(Bh + (wn + i * 16 + fr) * 32 + rq);
            }
#pragma unroll
            for (int i = 0; i < 4; i++)
#pragma unroll
                for (int j = 0; j < 4; j++)
                    acc[i][j] = __builtin_amdgcn_mfma_f32_16x16x32_bf16(
                        af[i], bfr[j], acc[i][j], 0, 0, 0);
        }
        __syncthreads();
        __builtin_amdgcn_sched_barrier(0);
    }

    // C/D layout: row = quad*4 + reg, col = lane&15  [m89-verified]
    const int gr0 = bm * 128 + wm + quad * 4;
    const int gc0 = bn * 128 + wn + fr;
#pragma unroll
    for (int i = 0; i < 4; i++)
#pragma unroll
        for (int j = 0; j < 4; j++)
#pragma unroll
            for (int r = 0; r < 4; r++) {
                int gr = gr0 + i * 16 + r;
                int gc = gc0 + j * 16;
                float val = acc[i][j][r];
                if (BF16OUT)
                    ((u16*)Cout)[(size_t)gr * N + gc] = f2bf(val);
                else
                    ((float*)Cout)[(size_t)gr * N + gc] = val;
            }
}

// ---- WKV body: r0-r7 measured-good scalar form (512 chain-groups x 64) -------
#define WTC 16

#define LOADCHUNK(KA, VA, RA, T0)                                        \
    _Pragma("unroll")                                                    \
    for (int s = 0; s < WTC; s++) {                                      \
        size_t idx = base + (size_t)((T0) + s) * Cdim;                   \
        KA[s] = kbf[idx]; VA[s] = vbf[idx]; RA[s] = rbf[idx];            \
    }

#define COMPCHUNK(KA, VA, RA, T0)                                        \
    _Pragma("unroll")                                                    \
    for (int s = 0; s < WTC; s++) {                                      \
        float kt = bf2f(KA[s]);                                          \
        float vt = bf2f(VA[s]);                                          \
        float rt = bf2f(RA[s]);                                          \
        float uk = u + kt;                                               \
        float no = fmaxf(o, uk);                                         \
        float Ae = __expf(o - no);                                       \
        float Bc = __expf(uk - no);                                      \
        float num = Ae * p + Bc * vt;                                    \
        float den = Ae * q + Bc;                                         \
        float y = num * __builtin_amdgcn_rcpf(den);                      \
        float sr = __builtin_amdgcn_rcpf(1.f + __expf(-rt));             \
        rwkv[base + (size_t)((T0) + s) * Cdim] = f2bf(y * sr);           \
        float wo = w + o;                                                \
        float no2 = fmaxf(wo, kt);                                       \
        float A2 = __expf(wo - no2);                                     \
        float B2 = __expf(kt - no2);                                     \
        p = A2 * p + B2 * vt;                                            \
        q = A2 * q + B2;                                                 \
        o = no2;                                                         \
    }

__device__ __forceinline__ void wkv_body(
    int blk, int lane,
    const u16* kbf, const u16* vbf, const u16* rbf,
    const float* td, const float* tfirst, u16* rwkv)
{
    int b = blk >> 4;
    int c = ((blk & 15) << 6) + lane;
    float w = -__expf(td[c]);
    float u = tfirst[c];
    const size_t base = (size_t)b * Tdim * Cdim + c;

    u32 kA[WTC], vA[WTC], rA[WTC];
    u32 kB[WTC], vB[WTC], rB[WTC];
    float p = 0.f, q = 0.f, o = -1e38f;

    LOADCHUNK(kA, vA, rA, 0)
    for (int t0 = 0; t0 < Tdim; t0 += 2 * WTC) {
        LOADCHUNK(kB, vB, rB, t0 + WTC)
        COMPCHUNK(kA, vA, rA, t0)
        if (t0 + 2 * WTC < Tdim) {
            LOADCHUNK(kA, vA, rA, t0 + 2 * WTC)
        }
        COMPCHUNK(kB, vB, rB, t0 + WTC)
    }
}

// ---- ONE cooperative megakernel: prep | 3x GEMM | wkv | gemmo ----------------
// All phases GRID-STRIDED -> correct at any grid size (launch can't be
// rejected for co-residency).  No __restrict__ on workspace pointers
// (rwkvb legally aliases xk).  Explicit __threadfence() (agent-scope
// release/acquire, the cross-XCD mechanism) around every grid.sync().
// Phase bodies = verified r8 code verbatim.
__global__ __launch_bounds__(256, 2) void fused_all(
    const float* x, const float* td, const float* tfi,
    const float* tmk, const float* tmv, const float* tmr,
    const float* Wk, const float* Wv, const float* Wr, const float* Wo,
    u16* xk, u16* xv, u16* xr,
    u16* wkb, u16* wvb, u16* wrb, u16* wob,
    u16* kbuf, u16* vbuf, u16* rbuf,
    u16* rwkvb, float* outp)
{
    __shared__ __align__(16) u16 Ls[2 * 16384];   // 64 KiB
    cg::grid_group grid = cg::this_grid();
    const int bx = blockIdx.x;
    const int tx = threadIdx.x;
    const int nb = gridDim.x;

    // ---- phase 0: prep (6144 virtual blocks) ----
    for (int v = bx; v < 6144; v += nb)
        prep_body(v, tx, x, tmk, tmv, tmr, xk, xv, xr,
                  Wk, Wv, Wr, Wo, wkb, wvb, wrb, wob);
    __threadfence();
    grid.sync();
    __threadfence();

    // ---- phase 1: k/v/r GEMMs (512 virtual tiles; XCD swizzle bm=v&63) ----
    for (int v = bx; v < 512; v += nb) {
        const int bm = v & 63, bn = v >> 6;
        gemm_body<1>(xk, wkb, (void*)kbuf, Ls, bm, bn);
        gemm_body<1>(xv, wvb, (void*)vbuf, Ls, bm, bn);
        gemm_body<1>(xr, wrb, (void*)rbuf, Ls, bm, bn);
    }
    __threadfence();
    grid.sync();
    __threadfence();

    // ---- phase 2: wkv scan (512 virtual blocks x 64 lanes, measured-good) ----
    for (int v = bx; v < 512; v += nb)
        if (tx < 64)
            wkv_body(v, tx, kbuf, vbuf, rbuf, td, tfi, rwkvb);
    __threadfence();
    grid.sync();
    __threadfence();

    // ---- phase 3: output GEMM (512 virtual tiles, f32 out) ----
    for (int v = bx; v < 512; v += nb) {
        const int bm = v & 63, bn = v >> 6;
        gemm_body<0>(rwkvb, wob, (void*)outp, Ls, bm, bn);
    }
}

// ---- standalone fallback kernels (r8-best four-launch path) ------------------
__global__ __launch_bounds__(256) void prep_fused(
    const float* x, const float* tmk, const float* tmv, const float* tmr,
    u16* xk, u16* xv, u16* xr,
    const float* w0, const float* w1, const float* w2, const float* w3,
    u16* o0, u16* o1, u16* o2, u16* o3)
{
    prep_body(blockIdx.x, threadIdx.x, x, tmk, tmv, tmr, xk, xv, xr,
              w0, w1, w2, w3, o0, o1, o2, o3);
}

__global__ __launch_bounds__(256) void gemm3_kernel(
    const u16* xk, const u16* xv, const u16* xr,
    const u16* wk, const u16* wv, const u16* wr,
    u16* ck, u16* cv, u16* cr)
{
    __shared__ __align__(16) u16 Ls[2 * 16384];
    const u16* A; const u16* Bw; u16* Cout;
    switch (blockIdx.z) {
        case 0:  A = xk; Bw = wk; Cout = ck; break;
        case 1:  A = xv; Bw = wv; Cout = cv; break;
        default: A = xr; Bw = wr; Cout = cr; break;
    }
    int bx = blockIdx.x;
    gemm_body<1>(A, Bw, (void*)Cout, Ls, bx & 63, bx >> 6);
}

__global__ __launch_bounds__(64) void wkv_kernel(
    const u16* kb, const u16* vb, const u16* rb,
    const float* td, const float* tfirst, u16* rwkv)
{
    wkv_body(blockIdx.x, threadIdx.x, kb, vb, rb, td, tfirst, rwkv);
}

__global__ __launch_bounds__(256) void gemmo_kernel(
    const u16* A, const u16* Bw, float* Cout)
{
    __shared__ __align__(16) u16 Ls[2 * 16384];
    int bx = blockIdx.x;
    gemm_body<0>(A, Bw, (void*)Cout, Ls, bx & 63, bx >> 6);
}

extern "C" void kernel_launch(void* const* d_in, const int* in_sizes, int n_in,
                              void* d_out, int out_size, void* d_ws, size_t ws_size,
                              hipStream_t stream) {
    (void)in_sizes; (void)n_in; (void)out_size; (void)ws_size;
    const float* x   = (const float*)d_in[0];
    const float* td  = (const float*)d_in[1];
    const float* tfi = (const float*)d_in[2];
    const float* tmk = (const float*)d_in[3];
    const float* tmv = (const float*)d_in[4];
    const float* tmr = (const float*)d_in[5];
    const float* Wk  = (const float*)d_in[6];
    const float* Wv  = (const float*)d_in[7];
    const float* Wr  = (const float*)d_in[8];
    const float* Wo  = (const float*)d_in[9];

    char* ws = (char*)d_ws;
    const size_t MiB = (size_t)1 << 20;
    u16* xk    = (u16*)(ws);             // [0,16)
    u16* xv    = (u16*)(ws + 16 * MiB);  // [16,32)
    u16* xr    = (u16*)(ws + 32 * MiB);  // [32,48)
    u16* wkb   = (u16*)(ws + 48 * MiB);  // [48,50)
    u16* wvb   = (u16*)(ws + 50 * MiB);  // [50,52)
    u16* wrb   = (u16*)(ws + 52 * MiB);  // [52,54)
    u16* wob   = (u16*)(ws + 54 * MiB);  // [54,56)
    u16* kbuf  = (u16*)(ws + 56 * MiB);  // [56,72)
    u16* vbuf  = (u16*)(ws + 72 * MiB);  // [72,88)
    u16* rbuf  = (u16*)(ws + 88 * MiB);  // [88,104)
    u16* rwkvb = (u16*)(ws);             // [0,16) — aliases xk (no restrict;
                                         //   xk dead after GEMM phase, fenced)
    float* outp = (float*)d_out;

    // occupancy-adaptive cooperative grid (host-side pure query; graph-legal).
    static int coopGrid = 0;
    if (coopGrid == 0) {
        int nbpc = 0;
        if (hipOccupancyMaxActiveBlocksPerMultiprocessor(&nbpc, fused_all, 256, 0)
                != hipSuccess || nbpc < 1)
            nbpc = 1;
        coopGrid = (nbpc >= 2) ? 512 : 256;
    }

    void* ka[] = {
        (void*)&x, (void*)&td, (void*)&tfi, (void*)&tmk, (void*)&tmv,
        (void*)&tmr, (void*)&Wk, (void*)&Wv, (void*)&Wr, (void*)&Wo,
        (void*)&xk, (void*)&xv, (void*)&xr, (void*)&wkb, (void*)&wvb,
        (void*)&wrb, (void*)&wob, (void*)&kbuf, (void*)&vbuf, (void*)&rbuf,
        (void*)&rwkvb, (void*)&outp
    };
    hipError_t cerr = hipLaunchCooperativeKernel((void*)fused_all,
                                                 dim3(coopGrid), dim3(256),
                                                 ka, 0, stream);
    if (cerr != hipSuccess) {
        // cooperative launch rejected (r9 lesson: never ignore the code) —
        // fall back to the verified r8-best four-launch path.
        (void)hipGetLastError();             // clear sticky error state
        prep_fused<<<6144, 256, 0, stream>>>(x, tmk, tmv, tmr, xk, xv, xr,
                                             Wk, Wv, Wr, Wo, wkb, wvb, wrb, wob);
        gemm3_kernel<<<dim3(512, 1, 3), 256, 0, stream>>>(xk, xv, xr,
                                                          wkb, wvb, wrb,
                                                          kbuf, vbuf, rbuf);
        wkv_kernel<<<512, 64, 0, stream>>>(kbuf, vbuf, rbuf, td, tfi, rwkvb);
        gemmo_kernel<<<512, 256, 0, stream>>>(rwkvb, wob, outp);
    }
}

// Round 13
// 223.089 us; speedup vs baseline: 2.3783x; 2.3783x over previous
//
#include <hip/hip_runtime.h>

#define Bdim 32
#define Tdim 256
#define Cdim 1024

typedef unsigned short u16;
typedef unsigned int u32;
typedef __bf16 bf16x8 __attribute__((ext_vector_type(8)));
typedef float f32x4 __attribute__((ext_vector_type(4)));

__device__ __forceinline__ float bf2f(u32 u) {
    union { u32 i; float f; } v; v.i = u << 16; return v.f;
}
__device__ __forceinline__ u16 f2bf(float f) {
    union { float f; u32 i; } v; v.f = f;
    u32 u = v.i;
    return (u16)((u + 0x7fffu + ((u >> 16) & 1u)) >> 16);  // RNE
}

__device__ __forceinline__ void gload16(const u16* g, u16* l) {
    __builtin_amdgcn_global_load_lds(
        (__attribute__((address_space(1))) const void*)g,
        (__attribute__((address_space(3))) void*)l, 16, 0, 0);
}

// ---- fused prep (x mixing -> bf16) + weight convert ---------------------------
__global__ __launch_bounds__(256) void prep_fused(
    const float* __restrict__ x, const float* __restrict__ tmk,
    const float* __restrict__ tmv, const float* __restrict__ tmr,
    u16* __restrict__ xk, u16* __restrict__ xv, u16* __restrict__ xr,
    const float* __restrict__ w0, const float* __restrict__ w1,
    const float* __restrict__ w2, const float* __restrict__ w3,
    u16* __restrict__ o0, u16* __restrict__ o1,
    u16* __restrict__ o2, u16* __restrict__ o3)
{
    int bid = blockIdx.x;
    if (bid < 4096) {
        int tid = bid * 256 + threadIdx.x;
        int e = tid << 3;
        int c = e & (Cdim - 1);
        int t = (e >> 10) & (Tdim - 1);
        float xf[8], xxf[8], mk[8], mv[8], mr[8];
        *(float4*)(xf)     = *(const float4*)(x + e);
        *(float4*)(xf + 4) = *(const float4*)(x + e + 4);
        if (t != 0) {
            *(float4*)(xxf)     = *(const float4*)(x + e - Cdim);
            *(float4*)(xxf + 4) = *(const float4*)(x + e - Cdim + 4);
        } else {
#pragma unroll
            for (int j = 0; j < 8; j++) xxf[j] = 0.f;
        }
        *(float4*)(mk)     = *(const float4*)(tmk + c);
        *(float4*)(mk + 4) = *(const float4*)(tmk + c + 4);
        *(float4*)(mv)     = *(const float4*)(tmv + c);
        *(float4*)(mv + 4) = *(const float4*)(tmv + c + 4);
        *(float4*)(mr)     = *(const float4*)(tmr + c);
        *(float4*)(mr + 4) = *(const float4*)(tmr + c + 4);
        u16 ok[8], ov[8], orr[8];
#pragma unroll
        for (int j = 0; j < 8; j++) {
            float d = xf[j] - xxf[j];
            ok[j]  = f2bf(xxf[j] + d * mk[j]);
            ov[j]  = f2bf(xxf[j] + d * mv[j]);
            orr[j] = f2bf(xxf[j] + d * mr[j]);
        }
        *(uint4*)(xk + e) = *(const uint4*)ok;
        *(uint4*)(xv + e) = *(const uint4*)ov;
        *(uint4*)(xr + e) = *(const uint4*)orr;
    } else {
        int wb = bid - 4096;                 // 0..2047
        int m = wb >> 9;                     // matrix 0..3
        const float* src; u16* dst;
        switch (m) {
            case 0: src = w0; dst = o0; break;
            case 1: src = w1; dst = o1; break;
            case 2: src = w2; dst = o2; break;
            default: src = w3; dst = o3; break;
        }
        int i = (((wb & 511) << 8) + threadIdx.x) << 3;
        float a[8];
        *(float4*)(a)     = *(const float4*)(src + i);
        *(float4*)(a + 4) = *(const float4*)(src + i + 4);
        u16 o[8];
#pragma unroll
        for (int j = 0; j < 8; j++) o[j] = f2bf(a[j]);
        *(uint4*)(dst + i) = *(const uint4*)o;
    }
}

// ---- GEMM body: C[8192,1024] = A[8192,1024] * Bw[1024,1024]^T (bf16 MFMA) -----
// Measured-best structure (r8: 61.7-61.9 us, MfmaUtil 34.3, 0 conflicts):
// 128x128 tile, BK=64, 4 waves (2Mx2N, wave-tile 64x64), double-buffered
// LDS (2x32 KiB, 2 blocks/CU), one-tile-ahead prefetch, __syncthreads tile
// boundaries (full drain + compiler fence; the bare-s_barrier variant raced
// in r5).  Session ledger: 3-ring counted-vmcnt (85.5), 2-phase fine (69),
// m201 256^2-port (70.4), wide-N 128x256 x3 (72-80), coop megakernel (530)
// all lost to this structure at this problem shape (K=1024, small grids).
// ROTATION SWIZZLE (r0-verified, 0 bank conflicts): LDS slot (row,pos)
// holds k-chunk (pos+((row>>1)&3))&3; writer thread t fetches global chunk
// ((t&3)+((t>>3)&3))&3; reader lane (fr,quad) reads pos=(quad-((fr>>1)&3))&3.
template <int BF16OUT>
__device__ __forceinline__ void gemm_body(
    const u16* __restrict__ A, const u16* __restrict__ Bw, void* __restrict__ Cout,
    u16* __restrict__ Ls, int bm, int bn)
{
    const int K = Cdim, N = Cdim;
    const int NT = K / 64;                   // 16 K-tiles
    const int tid = threadIdx.x;
    const int lane = tid & 63, wave = tid >> 6;
    const int wm = (wave & 1) << 6, wn = (wave >> 1) << 6;
    const int fr = lane & 15, quad = lane >> 4;

    const int srow = tid >> 2;
    const int skc = ((((tid & 3) + ((tid >> 3) & 3)) & 3) << 3);  // rotated chunk
    const u16* ga = A + (size_t)(bm * 128 + srow) * K + skc;
    const u16* gb = Bw + (size_t)(bn * 128 + srow) * K + skc;
    const size_t gstep = (size_t)64 * K;
    const int lw = wave << 9;                // wave-uniform LDS base (u16)

    auto stage = [&](int t, int buf) {
        const u16* gat = ga + t * 64;
        const u16* gbt = gb + t * 64;
        u16* base = Ls + buf * 16384 + lw;
        gload16(gat,              base);
        gload16(gat + gstep,      base + 2048);
        gload16(gbt,              base + 4096);
        gload16(gbt + gstep,      base + 4096 + 2048);
        gload16(gat + 32,         base + 8192);
        gload16(gat + 32 + gstep, base + 8192 + 2048);
        gload16(gbt + 32,         base + 12288);
        gload16(gbt + 32 + gstep, base + 12288 + 2048);
    };

    f32x4 acc[4][4];
#pragma unroll
    for (int i = 0; i < 4; i++)
#pragma unroll
        for (int j = 0; j < 4; j++)
            acc[i][j] = (f32x4){0.f, 0.f, 0.f, 0.f};

    const int rq = (((quad - ((fr >> 1) & 3)) & 3) << 3);  // reader pos (u16)

    stage(0, 0);
    __syncthreads();
    __builtin_amdgcn_sched_barrier(0);

#pragma unroll 1
    for (int t = 0; t < NT; ++t) {
        const int buf = t & 1;
        if (t + 1 < NT) stage(t + 1, buf ^ 1);   // prefetch next tile
        const u16* __restrict__ Tb = Ls + buf * 16384;
#pragma unroll
        for (int h = 0; h < 2; h++) {
            const u16* Ah = Tb + h * 8192;
            const u16* Bh = Tb + 4096 + h * 8192;
            bf16x8 af[4], bfr[4];
#pragma unroll
            for (int i = 0; i < 4; i++) {
                af[i]  = *(const bf16x8*)(Ah + (wm + i * 16 + fr) * 32 + rq);
                bfr[i] = *(const bf16x8*)(Bh + (wn + i * 16 + fr) * 32 + rq);
            }
#pragma unroll
            for (int i = 0; i < 4; i++)
#pragma unroll
                for (int j = 0; j < 4; j++)
                    acc[i][j] = __builtin_amdgcn_mfma_f32_16x16x32_bf16(
                        af[i], bfr[j], acc[i][j], 0, 0, 0);
        }
        __syncthreads();                     // prefetch landed during compute
        __builtin_amdgcn_sched_barrier(0);
    }

    // C/D layout: row = quad*4 + reg, col = lane&15  [m89-verified]
    const int gr0 = bm * 128 + wm + quad * 4;
    const int gc0 = bn * 128 + wn + fr;
#pragma unroll
    for (int i = 0; i < 4; i++)
#pragma unroll
        for (int j = 0; j < 4; j++)
#pragma unroll
            for (int r = 0; r < 4; r++) {
                int gr = gr0 + i * 16 + r;
                int gc = gc0 + j * 16;
                float val = acc[i][j][r];
                if (BF16OUT)
                    ((u16*)Cout)[(size_t)gr * N + gc] = f2bf(val);
                else
                    ((float*)Cout)[(size_t)gr * N + gc] = val;
            }
}

// grouped GEMM for k/v/r (blockIdx.z selects operand set), bf16 out
// XCD swizzle: bm = x&63 -> XCD = x%8 = bm%8, so all 8 bn-blocks sharing an
// A row-block co-reside on one XCD (per-XCD L2 working set fits).
__global__ __launch_bounds__(256) void gemm3_kernel(
    const u16* __restrict__ xk, const u16* __restrict__ xv, const u16* __restrict__ xr,
    const u16* __restrict__ wk, const u16* __restrict__ wv, const u16* __restrict__ wr,
    u16* __restrict__ ck, u16* __restrict__ cv, u16* __restrict__ cr)
{
    __shared__ __align__(16) u16 Ls[2 * 16384];   // 64 KiB double buffer
    const u16* A; const u16* Bw; u16* Cout;
    switch (blockIdx.z) {
        case 0:  A = xk; Bw = wk; Cout = ck; break;
        case 1:  A = xv; Bw = wv; Cout = cv; break;
        default: A = xr; Bw = wr; Cout = cr; break;
    }
    int bx = blockIdx.x;
    gemm_body<1>(A, Bw, (void*)Cout, Ls, bx & 63, bx >> 6);
}

// final GEMM, f32 out
__global__ __launch_bounds__(256) void gemmo_kernel(
    const u16* __restrict__ A, const u16* __restrict__ Bw, float* __restrict__ Cout)
{
    __shared__ __align__(16) u16 Ls[2 * 16384];
    int bx = blockIdx.x;
    gemm_body<0>(A, Bw, (void*)Cout, Ls, bx & 63, bx >> 6);
}

// ---- WKV scan + sigmoid(r) gate (r0-r7 measured-good 512x64 scalar form) ------
// r8's 2-channel ILP-2 variant at 256x64 regressed +14 us (1 wave/CU);
// this form keeps 512 waves (2/CU) and is latency-covered by the register
// double-buffered chunk prefetch.
#define WTC 16

#define LOADCHUNK(KA, VA, RA, T0)                                        \
    _Pragma("unroll")                                                    \
    for (int s = 0; s < WTC; s++) {                                      \
        size_t idx = base + (size_t)((T0) + s) * Cdim;                   \
        KA[s] = kb[idx]; VA[s] = vb[idx]; RA[s] = rb[idx];               \
    }

#define COMPCHUNK(KA, VA, RA, T0)                                        \
    _Pragma("unroll")                                                    \
    for (int s = 0; s < WTC; s++) {                                      \
        float kt = bf2f(KA[s]);                                          \
        float vt = bf2f(VA[s]);                                          \
        float rt = bf2f(RA[s]);                                          \
        float uk = u + kt;                                               \
        float no = fmaxf(o, uk);                                         \
        float Ae = __expf(o - no);                                       \
        float Bc = __expf(uk - no);                                      \
        float num = Ae * p + Bc * vt;                                    \
        float den = Ae * q + Bc;                                         \
        float y = num * __builtin_amdgcn_rcpf(den);                      \
        float sr = __builtin_amdgcn_rcpf(1.f + __expf(-rt));             \
        rwkv[base + (size_t)((T0) + s) * Cdim] = f2bf(y * sr);           \
        float wo = w + o;                                                \
        float no2 = fmaxf(wo, kt);                                       \
        float A2 = __expf(wo - no2);                                     \
        float B2 = __expf(kt - no2);                                     \
        p = A2 * p + B2 * vt;                                            \
        q = A2 * q + B2;                                                 \
        o = no2;                                                         \
    }

__global__ __launch_bounds__(64) void wkv_kernel(
    const u16* __restrict__ kb, const u16* __restrict__ vb,
    const u16* __restrict__ rb, const float* __restrict__ td,
    const float* __restrict__ tfirst, u16* __restrict__ rwkv)
{
    int lane = threadIdx.x;
    int blk = blockIdx.x;            // 512 blocks
    int b = blk >> 4;
    int c = ((blk & 15) << 6) + lane;
    float w = -__expf(td[c]);
    float u = tfirst[c];
    const size_t base = (size_t)b * Tdim * Cdim + c;

    u32 kA[WTC], vA[WTC], rA[WTC];
    u32 kB[WTC], vB[WTC], rB[WTC];
    float p = 0.f, q = 0.f, o = -1e38f;

    LOADCHUNK(kA, vA, rA, 0)
    for (int t0 = 0; t0 < Tdim; t0 += 2 * WTC) {
        LOADCHUNK(kB, vB, rB, t0 + WTC)
        COMPCHUNK(kA, vA, rA, t0)
        if (t0 + 2 * WTC < Tdim) {
            LOADCHUNK(kA, vA, rA, t0 + 2 * WTC)
        }
        COMPCHUNK(kB, vB, rB, t0 + WTC)
    }
}

extern "C" void kernel_launch(void* const* d_in, const int* in_sizes, int n_in,
                              void* d_out, int out_size, void* d_ws, size_t ws_size,
                              hipStream_t stream) {
    (void)in_sizes; (void)n_in; (void)out_size; (void)ws_size;
    const float* x   = (const float*)d_in[0];
    const float* td  = (const float*)d_in[1];
    const float* tfi = (const float*)d_in[2];
    const float* tmk = (const float*)d_in[3];
    const float* tmv = (const float*)d_in[4];
    const float* tmr = (const float*)d_in[5];
    const float* Wk  = (const float*)d_in[6];
    const float* Wv  = (const float*)d_in[7];
    const float* Wr  = (const float*)d_in[8];
    const float* Wo  = (const float*)d_in[9];

    char* ws = (char*)d_ws;
    const size_t MiB = (size_t)1 << 20;
    u16* xk    = (u16*)(ws);             // [0,16)
    u16* xv    = (u16*)(ws + 16 * MiB);  // [16,32)
    u16* xr    = (u16*)(ws + 32 * MiB);  // [32,48)
    u16* wkb   = (u16*)(ws + 48 * MiB);  // [48,50)
    u16* wvb   = (u16*)(ws + 50 * MiB);  // [50,52)
    u16* wrb   = (u16*)(ws + 52 * MiB);  // [52,54)
    u16* wob   = (u16*)(ws + 54 * MiB);  // [54,56)
    u16* kb    = (u16*)(ws + 56 * MiB);  // [56,72)
    u16* vb    = (u16*)(ws + 72 * MiB);  // [72,88)
    u16* rb    = (u16*)(ws + 88 * MiB);  // [88,104) — no alias: gemm3 z's run concurrently
    u16* rwkvb = (u16*)(ws);             // [0,16) — overlaps xk (dead after gemm3)

    prep_fused<<<6144, 256, 0, stream>>>(x, tmk, tmv, tmr, xk, xv, xr,
                                         Wk, Wv, Wr, Wo, wkb, wvb, wrb, wob);

    gemm3_kernel<<<dim3(512, 1, 3), 256, 0, stream>>>(xk, xv, xr, wkb, wvb, wrb,
                                                      kb, vb, rb);

    wkv_kernel<<<512, 64, 0, stream>>>(kb, vb, rb, td, tfi, rwkvb);

    gemmo_kernel<<<512, 256, 0, stream>>>(rwkvb, wob, (float*)d_out);
}